// Round 1
// 264.625 us; speedup vs baseline: 1.1959x; 1.1959x over previous
//
#include <hip/hip_runtime.h>
#include <hip/hip_bf16.h>
#include <math.h>

// ---------------- problem constants ----------------
#define NB 32
#define QL 32
#define DL 1024
#define EMB 300
#define EMBP 320            // padded K-dim per tap (zeros 300..319)
#define OD 128
#define KNUM 21
#define VOCAB 50000

typedef short short8 __attribute__((ext_vector_type(8)));
typedef float floatx4 __attribute__((ext_vector_type(4)));

// workspace layout (in float units)
static const size_t WP_OFF = 0;                        // packed bf16 weights (122880 f)
static const size_t DPK_OFF = 122880;                  // packed doc bf16 [32*1024][320]
static const size_t QPK_OFF = 5365760;                 // packed query bf16 [32*32][320] (contiguous after dpk!)
static const size_t QENC_OFF = 8122880;
static const size_t QENC_SZ = NB * QL * OD;            // 131072
static const size_t DENC_OFF = QENC_OFF + 3 * QENC_SZ;
static const size_t DENC_SZ = (size_t)NB * DL * OD;    // 4194304
static const size_t ACC_OFF = DENC_OFF + 3 * DENC_SZ;
static const int ACC_SZ = 9 * NB * QL * KNUM;          // 193536

// combined packed rows: doc (32768) + query (1024) + 2 zero guard rows
#define MROWS (NB * DL + NB * QL)      // 33792 = 264 * 128 exactly
#define MTILES 264
#define CONV_BLOCKS (MTILES * 3)       // 792, divisible by 8 (XCD swizzle bijective)

__device__ __constant__ int WPOFF_C[3] = {0, 40960, 122880};

__device__ __forceinline__ void gl_lds16(const ushort* g, char* l) {
    __builtin_amdgcn_global_load_lds(
        (const __attribute__((address_space(1))) unsigned int*)(g),
        (__attribute__((address_space(3))) unsigned int*)(l), 16, 0, 0);
}

// ---------------- weights -> bf16, layout [o][j*320+c] ----------------
__global__ void prep_w_kernel(const float* __restrict__ w1,
                              const float* __restrict__ w2,
                              const float* __restrict__ w3,
                              ushort* __restrict__ wp) {
    int idx = blockIdx.x * 256 + threadIdx.x;
    if (idx >= 245760) return;
    const float* src;
    int k, rel, base;
    if (idx < 40960)        { k = 1; rel = idx;          src = w1; base = 0; }
    else if (idx < 122880)  { k = 2; rel = idx - 40960;  src = w2; base = 40960; }
    else                    { k = 3; rel = idx - 122880; src = w3; base = 122880; }
    int kd = 320 * k;
    int o = rel / kd;
    int jc = rel - o * kd;
    int j = jc / EMBP;
    int c = jc - j * EMBP;
    float f = (c < EMB) ? src[(o * EMB + c) * k + j] : 0.f;
    __hip_bfloat16 h = __float2bfloat16(f);
    wp[base + rel] = *reinterpret_cast<ushort*>(&h);
}

// ---------------- gather token rows: fp32 emb -> packed bf16 [row][320] (doc + query + 2 zero rows) ----------------
__global__ void gather_pack(const float* __restrict__ emb,
                            const int* __restrict__ dids, const int* __restrict__ qids,
                            ushort* __restrict__ dpk, ushort* __restrict__ qpk) {
    int idx = blockIdx.x * 256 + threadIdx.x;    // one uint4 (8 bf16) per thread
    const int DROWS = NB * DL;
    if (idx >= (DROWS + NB * QL + 2) * 40) return;
    int r = idx / 40;
    int c0 = (idx - r * 40) * 8;
    int rid;
    ushort* dst;
    if (r < DROWS) { rid = dids[r]; dst = dpk + (size_t)r * EMBP; }
    else if (r < DROWS + NB * QL) { rid = qids[r - DROWS]; dst = qpk + (size_t)(r - DROWS) * EMBP; }
    else {
        // zero guard rows so the last conv tile's +2 row-shift stages finite data
        uint4 zz = {0u, 0u, 0u, 0u};
        *reinterpret_cast<uint4*>(qpk + (size_t)(r - DROWS) * EMBP + c0) = zz;
        return;
    }
    const float* erow = emb + (size_t)rid * EMB;
    ushort v[8];
    if (c0 + 8 <= EMB) {
        float4 f0 = *reinterpret_cast<const float4*>(erow + c0);
        float4 f1 = *reinterpret_cast<const float4*>(erow + c0 + 4);
        float fv[8] = {f0.x, f0.y, f0.z, f0.w, f1.x, f1.y, f1.z, f1.w};
#pragma unroll
        for (int i = 0; i < 8; ++i) {
            __hip_bfloat16 h = __float2bfloat16(fv[i]);
            v[i] = *reinterpret_cast<ushort*>(&h);
        }
    } else {
#pragma unroll
        for (int i = 0; i < 8; ++i) {
            int c = c0 + i;
            float f = (c < EMB) ? erow[c] : 0.f;
            __hip_bfloat16 h = __float2bfloat16(f);
            v[i] = *reinterpret_cast<ushort*>(&h);
        }
    }
    *reinterpret_cast<uint4*>(dst + c0) = *reinterpret_cast<uint4*>(v);
}

// ---------------- conv as one flattened GEMM: LDS-staged (global_load_lds w=16), double-buffered, 2-phase ----------------
// M = 33792 combined rows (doc then query, contiguous), N = 128, K = 320*(z+1) with per-tap row shift.
// Grid: 792 blocks (264 tiles x 3 z, XCD-swizzled so a tile's z-triple shares an XCD L2).
// Block: 256 thr = 4 waves (2m x 2n), each wave 64x64 of the 128x128 tile, BK=64.
// LDS per buffer: A[130 rows][64] bf16 (16640 B) + B[128][64] bf16 (16384 B); x2 buffers = 66048 B -> 2 blocks/CU.
__global__ __launch_bounds__(256) void conv_mfma(const ushort* __restrict__ xpk,
                                                 const float* __restrict__ dmask,
                                                 const float* __restrict__ qmask,
                                                 const ushort* __restrict__ wp,
                                                 const float* __restrict__ b1,
                                                 const float* __restrict__ b2,
                                                 const float* __restrict__ b3,
                                                 float* __restrict__ denc,
                                                 float* __restrict__ qenc) {
    __shared__ __align__(16) char smem[2][33024];

    const int tid = threadIdx.x;
    const int bid = blockIdx.x;
    // XCD-bijective swizzle: 792 = 8 * 99; consecutive swz ids land on one XCD
    const int swz = (bid & 7) * (CONV_BLOCKS / 8) + (bid >> 3);
    const int z = swz % 3;
    const int tile = swz / 3;
    const int l0 = tile * 128;

    const int Kdim = EMBP * (z + 1);
    const int nk = 5 * (z + 1);                 // K-steps of 64
    const ushort* wpk = wp + WPOFF_C[z];
    const float* bias = (z == 0) ? b1 : ((z == 1) ? b2 : b3);

    const int wave = tid >> 6;
    const int lane = tid & 63;
    const int l15 = lane & 15;
    const int quad = lane >> 4;
    const int wm = wave >> 1;
    const int wn = wave & 1;

    // per-lane staging source bases: lane -> (row = p*32 + wave*8 + lane/8, col = (lane&7)*8)
    const int srow = lane >> 3;
    const int scol = (lane & 7) * 8;
    const ushort* a0 = xpk + (size_t)(l0 + wave * 8 + srow) * EMBP + scol;
    const ushort* at = xpk + (size_t)(l0 + 128 + srow) * EMBP + scol;   // tail rows 128..129 (lanes 0..15)
    const ushort* b0 = wpk + (size_t)(wave * 8 + srow) * Kdim + scol;

    auto stage = [&](int buf, int kk) {
        int jj = (kk >= 10) ? 2 : ((kk >= 5) ? 1 : 0);
        int coff = (kk - jj * 5) * 64;          // A col within the 320-wide row
        int koff = kk * 64;                     // B col within Kdim
        char* abuf = smem[buf];
        char* bbuf = smem[buf] + 16640;
#pragma unroll
        for (int p = 0; p < 4; ++p)
            gl_lds16(a0 + p * (32 * EMBP) + coff, abuf + p * 4096 + wave * 1024);
        if (wave == 0 && lane < 16)
            gl_lds16(at + coff, abuf + 16384);
#pragma unroll
        for (int p = 0; p < 4; ++p)
            gl_lds16(b0 + (size_t)p * 32 * Kdim + koff, bbuf + p * 4096 + wave * 1024);
    };

    floatx4 acc[4][4];
#pragma unroll
    for (int i = 0; i < 4; ++i)
#pragma unroll
        for (int j = 0; j < 4; ++j) acc[i][j] = (floatx4)0.f;

    stage(0, 0);
    __syncthreads();                            // drains vmcnt(0): buf0 ready

    int jjc = 0, ccc = 0;
    int buf = 0;
    for (int kk = 0; kk < nk; ++kk) {
        if (kk + 1 < nk) stage(buf ^ 1, kk + 1);   // async prefetch next K-step
        const char* Ab = smem[buf];
        const char* Bb = smem[buf] + 16640;
        short8 af[2][4], bf[2][4];
#pragma unroll
        for (int h = 0; h < 2; ++h)
#pragma unroll
            for (int i = 0; i < 4; ++i) {
                af[h][i] = *reinterpret_cast<const short8*>(
                    Ab + (wm * 64 + i * 16 + l15 + jjc) * 128 + h * 64 + quad * 16);
                bf[h][i] = *reinterpret_cast<const short8*>(
                    Bb + (wn * 64 + i * 16 + l15) * 128 + h * 64 + quad * 16);
            }
#pragma unroll
        for (int h = 0; h < 2; ++h)
#pragma unroll
            for (int i = 0; i < 4; ++i)
#pragma unroll
                for (int j = 0; j < 4; ++j)
                    acc[i][j] = __builtin_amdgcn_mfma_f32_16x16x32_bf16(af[h][i], bf[h][j], acc[i][j], 0, 0, 0);
        ++ccc;
        if (ccc == 5) { ccc = 0; ++jjc; }
        __syncthreads();                        // drain prefetch + all ds_reads before buffer swap
        buf ^= 1;
    }

    // ---- epilogue: bias + relu + row L2-norm + mask; rowsum aliases staging LDS ----
    float (*rowsum)[128] = reinterpret_cast<float(*)[128]>(smem);
    float bv[4];
#pragma unroll
    for (int j = 0; j < 4; ++j) bv[j] = bias[wn * 64 + j * 16 + l15];
#pragma unroll
    for (int i = 0; i < 4; ++i)
#pragma unroll
        for (int r = 0; r < 4; ++r) {
            float p = 0.f;
#pragma unroll
            for (int j = 0; j < 4; ++j) {
                float y = fmaxf(acc[i][j][r] + bv[j], 0.f);
                acc[i][j][r] = y;
                p += y * y;
            }
#pragma unroll
            for (int m = 1; m < 16; m <<= 1) p += __shfl_xor(p, m, 64);
            if (l15 == 0) rowsum[wn][wm * 64 + i * 16 + quad * 4 + r] = p;
        }
    __syncthreads();

#pragma unroll
    for (int i = 0; i < 4; ++i) {
#pragma unroll
        for (int rr = 0; rr < 4; ++rr) {
            int rl = wm * 64 + i * 16 + quad * 4 + rr;
            int r = l0 + rl;                    // global combined row
            float tot = rowsum[0][rl] + rowsum[1][rl];
            float mv;
            float* op;
            if (r < NB * DL) {
                int l = r & (DL - 1);
                if (l >= DL - z) continue;      // invalid (cross-batch shift), masked downstream
                mv = dmask[r];
                op = denc + (size_t)z * DENC_SZ + (size_t)r * OD;
            } else {
                int t = r - NB * DL;
                int l = t & (QL - 1);
                if (l >= QL - z) continue;
                mv = qmask[t];
                op = qenc + (size_t)z * QENC_SZ + (size_t)t * OD;
            }
            float sc = mv / (sqrtf(tot) + 1e-13f);
            float* pp = op + wn * 64 + l15;
#pragma unroll
            for (int j = 0; j < 4; ++j) pp[j * 16] = acc[i][j][rr] * sc;
        }
    }
}

// ---------------- matcher: split-precision MFMA dots + gaussian histogram ----------------
// grid: (vtile=8, b=32, pair=9), block 256 = 4 waves. Tile 32q x 128v, K=128 in 2 chunks of 64.
// s = hiQ*hiV + hiQ*loV + loQ*hiV  (3 chained bf16 MFMAs; error ~1e-5, preserves sigma=0.001 kernel)
__global__ __launch_bounds__(256) void matcher_kernel(const float* __restrict__ qenc,
                                                      const float* __restrict__ denc,
                                                      float* __restrict__ accb) {
    __shared__ __align__(16) ushort ldsbuf[23040];   // 46 KB; S (32x130 f32) aliases after dots
    const int QH = 0, QLo = 2304, VH = 4608, VLo = 13824;

    const int tid = threadIdx.x;
    const int pp = blockIdx.z;
    const int b = blockIdx.y;
    const int v0 = blockIdx.x * 128;
    const int qi = pp / 3;
    const int di = pp - qi * 3;
    const int Vk = 1024 - di;
    const float* qptr = qenc + qi * QENC_SZ + (size_t)b * (QL * OD);
    const float* vptr = denc + di * DENC_SZ + (size_t)b * (DL * OD);

    const int wave = tid >> 6;
    const int lane = tid & 63;
    const int l15 = lane & 15;
    const int quad = lane >> 4;

    floatx4 acc[2][2];
#pragma unroll
    for (int i = 0; i < 2; ++i)
#pragma unroll
        for (int j = 0; j < 2; ++j) acc[i][j] = (floatx4)0.f;

    // staging maps
    const int qrow = tid >> 3, qseg = (tid & 7) * 8;        // Q: 32 rows x 8 segs
    const int vrow = tid >> 1, vseg = (tid & 1) * 32;       // V: 128 rows x 2 segs

    for (int ch = 0; ch < 2; ++ch) {
        const int k0 = ch * 64;
        // ---- stage Q (hi/lo split) ----
        {
            const float* src = qptr + qrow * OD + k0 + qseg;
            float4 f0 = *reinterpret_cast<const float4*>(src);
            float4 f1 = *reinterpret_cast<const float4*>(src + 4);
            float fv[8] = {f0.x, f0.y, f0.z, f0.w, f1.x, f1.y, f1.z, f1.w};
            ushort hi8[8], lo8[8];
#pragma unroll
            for (int i = 0; i < 8; ++i) {
                __hip_bfloat16 h = __float2bfloat16(fv[i]);
                float hf = __bfloat162float(h);
                __hip_bfloat16 l = __float2bfloat16(fv[i] - hf);
                hi8[i] = *reinterpret_cast<ushort*>(&h);
                lo8[i] = *reinterpret_cast<ushort*>(&l);
            }
            *reinterpret_cast<uint4*>(&ldsbuf[QH + qrow * 72 + qseg]) = *reinterpret_cast<uint4*>(hi8);
            *reinterpret_cast<uint4*>(&ldsbuf[QLo + qrow * 72 + qseg]) = *reinterpret_cast<uint4*>(lo8);
        }
        // ---- stage V (hi/lo split) ----
        {
            const float* src = vptr + (size_t)(v0 + vrow) * OD + k0 + vseg;
#pragma unroll
            for (int g = 0; g < 4; ++g) {
                float4 f0 = *reinterpret_cast<const float4*>(src + g * 8);
                float4 f1 = *reinterpret_cast<const float4*>(src + g * 8 + 4);
                float fv[8] = {f0.x, f0.y, f0.z, f0.w, f1.x, f1.y, f1.z, f1.w};
                ushort hi8[8], lo8[8];
#pragma unroll
                for (int i = 0; i < 8; ++i) {
                    __hip_bfloat16 h = __float2bfloat16(fv[i]);
                    float hf = __bfloat162float(h);
                    __hip_bfloat16 l = __float2bfloat16(fv[i] - hf);
                    hi8[i] = *reinterpret_cast<ushort*>(&h);
                    lo8[i] = *reinterpret_cast<ushort*>(&l);
                }
                *reinterpret_cast<uint4*>(&ldsbuf[VH + vrow * 72 + vseg + g * 8]) = *reinterpret_cast<uint4*>(hi8);
                *reinterpret_cast<uint4*>(&ldsbuf[VLo + vrow * 72 + vseg + g * 8]) = *reinterpret_cast<uint4*>(lo8);
            }
        }
        __syncthreads();
        // ---- MFMA: wave owns v-range [wave*32, wave*32+32) ----
#pragma unroll
        for (int kf = 0; kf < 2; ++kf) {
            const int ko = kf * 32 + (quad << 3);
            short8 qh[2], ql[2], vh[2], vl[2];
#pragma unroll
            for (int i = 0; i < 2; ++i) {
                qh[i] = *reinterpret_cast<const short8*>(&ldsbuf[QH + (i * 16 + l15) * 72 + ko]);
                ql[i] = *reinterpret_cast<const short8*>(&ldsbuf[QLo + (i * 16 + l15) * 72 + ko]);
                int n = wave * 32 + i * 16 + l15;
                vh[i] = *reinterpret_cast<const short8*>(&ldsbuf[VH + n * 72 + ko]);
                vl[i] = *reinterpret_cast<const short8*>(&ldsbuf[VLo + n * 72 + ko]);
            }
#pragma unroll
            for (int i = 0; i < 2; ++i)
#pragma unroll
                for (int j = 0; j < 2; ++j) {
                    acc[i][j] = __builtin_amdgcn_mfma_f32_16x16x32_bf16(qh[i], vh[j], acc[i][j], 0, 0, 0);
                    acc[i][j] = __builtin_amdgcn_mfma_f32_16x16x32_bf16(qh[i], vl[j], acc[i][j], 0, 0, 0);
                    acc[i][j] = __builtin_amdgcn_mfma_f32_16x16x32_bf16(ql[i], vh[j], acc[i][j], 0, 0, 0);
                }
        }
        __syncthreads();
    }

    // ---- S tile to LDS (stride 130 f32), poison v >= vmax with 1e4 ----
    float* Sm = reinterpret_cast<float*>(ldsbuf);
    const int vmax = min(128, Vk - v0);
#pragma unroll
    for (int i = 0; i < 2; ++i)
#pragma unroll
        for (int j = 0; j < 2; ++j)
#pragma unroll
            for (int r = 0; r < 4; ++r) {
                int q = i * 16 + quad * 4 + r;
                int v = wave * 32 + j * 16 + l15;
                float val = acc[i][j][r];
                if (v >= vmax) val = 1.0e4f;
                Sm[q * 130 + v] = val;
            }
    __syncthreads();

    // ---- gaussian phase: thread = (q, t), one accumulator, float2 reads (2-way free) ----
    for (int idx = tid; idx < 32 * KNUM; idx += 256) {
        int q = idx & 31;
        int t = idx >> 5;
        float mu = (t == 0) ? 1.0f : 0.95f - 0.1f * (float)(t - 1);
        float Am = (t == 0) ? -721347.52f : -72.13475204f;   // -log2e/(2 sigma^2)
        const float* srow = &Sm[q * 130];
        float a = 0.f;
#pragma unroll 8
        for (int j = 0; j < 64; ++j) {
            float2 s2 = *reinterpret_cast<const float2*>(&srow[2 * j]);
            float d0 = s2.x - mu;
            float d1 = s2.y - mu;
            a += __builtin_exp2f(Am * d0 * d0);
            a += __builtin_exp2f(Am * d1 * d1);
        }
        atomicAdd(&accb[((pp * NB + b) * QL + q) * KNUM + t], a);
    }
}

// ---------------- finalize ----------------
__global__ void finalize_kernel(const float* __restrict__ accb,
                                const float* __restrict__ qmask,
                                const float* __restrict__ dw,
                                const float* __restrict__ db,
                                float* __restrict__ out) {
    __shared__ float prod[192];
    int b = blockIdx.x;
    int tid = threadIdx.x;
    if (tid < 189) {
        int pq = tid / 21;
        int t = tid - pq * 21;
        int qi = pq / 3;
        int Qk = 32 - qi;
        const float* ab = accb + ((pq * NB + b) * QL) * KNUM + t;
        float s = 0.f;
        for (int q = 0; q < Qk; ++q)
            s += logf(fmaxf(ab[q * KNUM], 1e-10f)) * qmask[b * QL + q];
        float lg = s * 0.01f;
        out[NB + b * 189 + tid] = lg;
        prod[tid] = lg * dw[tid];
    }
    __syncthreads();
    if (tid == 0) {
        float sc = db[0];
        for (int i = 0; i < 189; ++i) sc += prod[i];
        out[b] = sc;
    }
}

// ---------------- launcher ----------------
extern "C" void kernel_launch(void* const* d_in, const int* in_sizes, int n_in,
                              void* d_out, int out_size, void* d_ws, size_t ws_size,
                              hipStream_t stream) {
    const int* qids = (const int*)d_in[0];
    const float* qmask = (const float*)d_in[1];
    const int* dids = (const int*)d_in[2];
    const float* dmask = (const float*)d_in[3];
    const float* emb = (const float*)d_in[4];
    const float* w1 = (const float*)d_in[5];
    const float* b1 = (const float*)d_in[6];
    const float* w2 = (const float*)d_in[7];
    const float* b2 = (const float*)d_in[8];
    const float* w3 = (const float*)d_in[9];
    const float* b3 = (const float*)d_in[10];
    const float* dw = (const float*)d_in[11];
    const float* db = (const float*)d_in[12];
    float* out = (float*)d_out;
    float* ws = (float*)d_ws;

    ushort* wp = (ushort*)(ws + WP_OFF);
    ushort* dpk = (ushort*)(ws + DPK_OFF);
    ushort* qpk = (ushort*)(ws + QPK_OFF);
    float* qenc = ws + QENC_OFF;
    float* denc = ws + DENC_OFF;
    float* accb = ws + ACC_OFF;

    hipMemsetAsync(accb, 0, ACC_SZ * sizeof(float), stream);
    prep_w_kernel<<<960, 256, 0, stream>>>(w1, w2, w3, wp);
    gather_pack<<<((MROWS + 2) * 40 + 255) / 256, 256, 0, stream>>>(emb, dids, qids, dpk, qpk);

    conv_mfma<<<CONV_BLOCKS, 256, 0, stream>>>(dpk, dmask, qmask, wp, b1, b2, b3, denc, qenc);

    matcher_kernel<<<dim3(8, NB, 9), 256, 0, stream>>>(qenc, denc, accb);
    finalize_kernel<<<NB, 256, 0, stream>>>(accb, qmask, dw, db, out);
}

// Round 2
// 254.518 us; speedup vs baseline: 1.2434x; 1.0397x over previous
//
#include <hip/hip_runtime.h>
#include <hip/hip_bf16.h>
#include <math.h>

// ---------------- problem constants ----------------
#define NB 32
#define QL 32
#define DL 1024
#define EMB 300
#define EMBP 320            // padded K-dim per tap (zeros 300..319)
#define OD 128
#define KNUM 21
#define VOCAB 50000

typedef short short8 __attribute__((ext_vector_type(8)));
typedef float floatx4 __attribute__((ext_vector_type(4)));

// workspace layout (in float units)
static const size_t WP_OFF  = 0;           // packed bf16 weights: 245760 ushorts = 122880 fl
static const size_t DPK_OFF = 122880;      // packed doc bf16 [32*1024][320] = 5242880 fl
static const size_t QPK_OFF = 5365760;     // packed query bf16 [(1024+2)][320] = 164160 fl
// encoder outputs stored as SPLIT bf16 hi/lo planes (replaces old f32 enc; same total bytes)
static const size_t QH_OFF  = 5529920;     // qenc hi: 3 * 32*32*128 us = 196608 fl
static const size_t QLO_OFF = 5726528;     // qenc lo
static const size_t DH_OFF  = 5923136;     // denc hi: 3 * 32*1024*128 us = 6291456 fl
static const size_t DLO_OFF = 12214592;    // denc lo
static const size_t ACC_OFF = 18506048;
static const int ACC_SZ = 9 * NB * QL * KNUM;          // 193536

#define QPLANE 131072      // ushorts per z-plane of qenc (32*32*128)
#define DPLANE 4194304     // ushorts per z-plane of denc (32*1024*128)

// combined packed rows: doc (32768) + query (1024) + 2 zero guard rows
#define MROWS (NB * DL + NB * QL)      // 33792 = 264 * 128 exactly
#define MTILES 264
#define CONV_BLOCKS (MTILES * 3)       // 792, divisible by 8 (XCD swizzle bijective)

__device__ __constant__ int WPOFF_C[3] = {0, 40960, 122880};

__device__ __forceinline__ void gl_lds16(const ushort* g, char* l) {
    __builtin_amdgcn_global_load_lds(
        (const __attribute__((address_space(1))) unsigned int*)(g),
        (__attribute__((address_space(3))) unsigned int*)(l), 16, 0, 0);
}

__device__ __forceinline__ ushort bf16_bits(float f) {
    __hip_bfloat16 h = __float2bfloat16(f);
    return *reinterpret_cast<ushort*>(&h);
}

// ---------------- weights -> bf16, layout [o][j*320+c] ----------------
__global__ void prep_w_kernel(const float* __restrict__ w1,
                              const float* __restrict__ w2,
                              const float* __restrict__ w3,
                              ushort* __restrict__ wp) {
    int idx = blockIdx.x * 256 + threadIdx.x;
    if (idx >= 245760) return;
    const float* src;
    int k, rel, base;
    if (idx < 40960)        { k = 1; rel = idx;          src = w1; base = 0; }
    else if (idx < 122880)  { k = 2; rel = idx - 40960;  src = w2; base = 40960; }
    else                    { k = 3; rel = idx - 122880; src = w3; base = 122880; }
    int kd = 320 * k;
    int o = rel / kd;
    int jc = rel - o * kd;
    int j = jc / EMBP;
    int c = jc - j * EMBP;
    float f = (c < EMB) ? src[(o * EMB + c) * k + j] : 0.f;
    wp[base + rel] = bf16_bits(f);
}

// ---------------- gather token rows: fp32 emb -> packed bf16 [row][320] (doc + query + 2 zero rows) ----------------
__global__ void gather_pack(const float* __restrict__ emb,
                            const int* __restrict__ dids, const int* __restrict__ qids,
                            ushort* __restrict__ dpk, ushort* __restrict__ qpk) {
    int idx = blockIdx.x * 256 + threadIdx.x;    // one uint4 (8 bf16) per thread
    const int DROWS = NB * DL;
    if (idx >= (DROWS + NB * QL + 2) * 40) return;
    int r = idx / 40;
    int c0 = (idx - r * 40) * 8;
    int rid;
    ushort* dst;
    if (r < DROWS) { rid = dids[r]; dst = dpk + (size_t)r * EMBP; }
    else if (r < DROWS + NB * QL) { rid = qids[r - DROWS]; dst = qpk + (size_t)(r - DROWS) * EMBP; }
    else {
        uint4 zz = {0u, 0u, 0u, 0u};
        *reinterpret_cast<uint4*>(qpk + (size_t)(r - DROWS) * EMBP + c0) = zz;
        return;
    }
    const float* erow = emb + (size_t)rid * EMB;
    ushort v[8];
    if (c0 + 8 <= EMB) {
        float4 f0 = *reinterpret_cast<const float4*>(erow + c0);
        float4 f1 = *reinterpret_cast<const float4*>(erow + c0 + 4);
        float fv[8] = {f0.x, f0.y, f0.z, f0.w, f1.x, f1.y, f1.z, f1.w};
#pragma unroll
        for (int i = 0; i < 8; ++i) v[i] = bf16_bits(fv[i]);
    } else {
#pragma unroll
        for (int i = 0; i < 8; ++i) {
            int c = c0 + i;
            v[i] = bf16_bits((c < EMB) ? erow[c] : 0.f);
        }
    }
    *reinterpret_cast<uint4*>(dst + c0) = *reinterpret_cast<uint4*>(v);
}

// ---------------- conv as one flattened GEMM: LDS-staged (global_load_lds w=16), double-buffered ----------------
// Epilogue now emits bf16 hi/lo split planes directly (bit-identical to the old in-matcher split).
__global__ __launch_bounds__(256) void conv_mfma(const ushort* __restrict__ xpk,
                                                 const float* __restrict__ dmask,
                                                 const float* __restrict__ qmask,
                                                 const ushort* __restrict__ wp,
                                                 const float* __restrict__ b1,
                                                 const float* __restrict__ b2,
                                                 const float* __restrict__ b3,
                                                 ushort* __restrict__ dh,
                                                 ushort* __restrict__ dlo,
                                                 ushort* __restrict__ qh,
                                                 ushort* __restrict__ qlo) {
    __shared__ __align__(16) char smem[2][33024];

    const int tid = threadIdx.x;
    const int bid = blockIdx.x;
    // XCD-bijective swizzle: 792 = 8 * 99
    const int swz = (bid & 7) * (CONV_BLOCKS / 8) + (bid >> 3);
    const int z = swz % 3;
    const int tile = swz / 3;
    const int l0 = tile * 128;

    const int Kdim = EMBP * (z + 1);
    const int nk = 5 * (z + 1);                 // K-steps of 64
    const ushort* wpk = wp + WPOFF_C[z];
    const float* bias = (z == 0) ? b1 : ((z == 1) ? b2 : b3);

    const int wave = tid >> 6;
    const int lane = tid & 63;
    const int l15 = lane & 15;
    const int quad = lane >> 4;
    const int wm = wave >> 1;
    const int wn = wave & 1;

    const int srow = lane >> 3;
    const int scol = (lane & 7) * 8;
    const ushort* a0 = xpk + (size_t)(l0 + wave * 8 + srow) * EMBP + scol;
    const ushort* at = xpk + (size_t)(l0 + 128 + srow) * EMBP + scol;   // tail rows 128..129
    const ushort* b0 = wpk + (size_t)(wave * 8 + srow) * Kdim + scol;

    auto stage = [&](int buf, int kk) {
        int jj = (kk >= 10) ? 2 : ((kk >= 5) ? 1 : 0);
        int coff = (kk - jj * 5) * 64;
        int koff = kk * 64;
        char* abuf = smem[buf];
        char* bbuf = smem[buf] + 16640;
#pragma unroll
        for (int p = 0; p < 4; ++p)
            gl_lds16(a0 + p * (32 * EMBP) + coff, abuf + p * 4096 + wave * 1024);
        if (wave == 0 && lane < 16)
            gl_lds16(at + coff, abuf + 16384);
#pragma unroll
        for (int p = 0; p < 4; ++p)
            gl_lds16(b0 + (size_t)p * 32 * Kdim + koff, bbuf + p * 4096 + wave * 1024);
    };

    floatx4 acc[4][4];
#pragma unroll
    for (int i = 0; i < 4; ++i)
#pragma unroll
        for (int j = 0; j < 4; ++j) acc[i][j] = (floatx4)0.f;

    stage(0, 0);
    __syncthreads();

    int jjc = 0, ccc = 0;
    int buf = 0;
    for (int kk = 0; kk < nk; ++kk) {
        if (kk + 1 < nk) stage(buf ^ 1, kk + 1);
        const char* Ab = smem[buf];
        const char* Bb = smem[buf] + 16640;
        short8 af[2][4], bf[2][4];
#pragma unroll
        for (int h = 0; h < 2; ++h)
#pragma unroll
            for (int i = 0; i < 4; ++i) {
                af[h][i] = *reinterpret_cast<const short8*>(
                    Ab + (wm * 64 + i * 16 + l15 + jjc) * 128 + h * 64 + quad * 16);
                bf[h][i] = *reinterpret_cast<const short8*>(
                    Bb + (wn * 64 + i * 16 + l15) * 128 + h * 64 + quad * 16);
            }
#pragma unroll
        for (int h = 0; h < 2; ++h)
#pragma unroll
            for (int i = 0; i < 4; ++i)
#pragma unroll
                for (int j = 0; j < 4; ++j)
                    acc[i][j] = __builtin_amdgcn_mfma_f32_16x16x32_bf16(af[h][i], bf[h][j], acc[i][j], 0, 0, 0);
        ++ccc;
        if (ccc == 5) { ccc = 0; ++jjc; }
        __syncthreads();
        buf ^= 1;
    }

    // ---- epilogue: bias + relu + row L2-norm + mask; emit bf16 hi/lo planes ----
    float (*rowsum)[128] = reinterpret_cast<float(*)[128]>(smem);
    float bv[4];
#pragma unroll
    for (int j = 0; j < 4; ++j) bv[j] = bias[wn * 64 + j * 16 + l15];
#pragma unroll
    for (int i = 0; i < 4; ++i)
#pragma unroll
        for (int r = 0; r < 4; ++r) {
            float p = 0.f;
#pragma unroll
            for (int j = 0; j < 4; ++j) {
                float y = fmaxf(acc[i][j][r] + bv[j], 0.f);
                acc[i][j][r] = y;
                p += y * y;
            }
#pragma unroll
            for (int m = 1; m < 16; m <<= 1) p += __shfl_xor(p, m, 64);
            if (l15 == 0) rowsum[wn][wm * 64 + i * 16 + quad * 4 + r] = p;
        }
    __syncthreads();

#pragma unroll
    for (int i = 0; i < 4; ++i) {
#pragma unroll
        for (int rr = 0; rr < 4; ++rr) {
            int rl = wm * 64 + i * 16 + quad * 4 + rr;
            int r = l0 + rl;                    // global combined row
            float tot = rowsum[0][rl] + rowsum[1][rl];
            float mv;
            ushort* hp;
            ushort* lp;
            if (r < NB * DL) {
                int l = r & (DL - 1);
                if (l >= DL - z) continue;
                mv = dmask[r];
                size_t base = (size_t)z * DPLANE + (size_t)r * OD;
                hp = dh + base; lp = dlo + base;
            } else {
                int t = r - NB * DL;
                int l = t & (QL - 1);
                if (l >= QL - z) continue;
                mv = qmask[t];
                size_t base = (size_t)z * QPLANE + (size_t)t * OD;
                hp = qh + base; lp = qlo + base;
            }
            float sc = mv / (sqrtf(tot) + 1e-13f);
            int cb = wn * 64 + l15;
#pragma unroll
            for (int j = 0; j < 4; ++j) {
                float v = acc[i][j][rr] * sc;
                __hip_bfloat16 h = __float2bfloat16(v);
                float hf = __bfloat162float(h);
                hp[cb + j * 16] = *reinterpret_cast<ushort*>(&h);
                __hip_bfloat16 l = __float2bfloat16(v - hf);
                lp[cb + j * 16] = *reinterpret_cast<ushort*>(&l);
            }
        }
    }
}

// ---------------- matcher: direct global->VGPR MFMA (no staging LDS), then gaussian histogram ----------------
// grid: (vtile=8, b=32, pair=9), block 256 = 4 waves. Tile 32q x 128v, K=128 in 4 windows of 32.
// s = hiQ*hiV + hiQ*loV + loQ*hiV  (3 chained bf16 MFMAs; bit-identical to previous rounds)
// Each wave owns v rows [wave*32, wave*32+32): V frags are wave-private, Q frags re-read from L1/L2.
__global__ __launch_bounds__(256) void matcher_kernel(const ushort* __restrict__ qh_g,
                                                      const ushort* __restrict__ ql_g,
                                                      const ushort* __restrict__ vh_g,
                                                      const ushort* __restrict__ vl_g,
                                                      float* __restrict__ accb) {
    __shared__ __align__(16) float Sm[32 * 132];     // 16.9 KB; stride 132 = 16B-aligned float4 rows

    const int tid = threadIdx.x;
    const int pp = blockIdx.z;
    const int b = blockIdx.y;
    const int v0 = blockIdx.x * 128;
    const int qi = pp / 3;
    const int di = pp - qi * 3;
    const int Vk = 1024 - di;

    const ushort* qhb = qh_g + (size_t)qi * QPLANE + (size_t)b * (QL * OD);
    const ushort* qlb = ql_g + (size_t)qi * QPLANE + (size_t)b * (QL * OD);
    const ushort* vhb = vh_g + (size_t)di * DPLANE + (size_t)b * (DL * OD) + (size_t)v0 * OD;
    const ushort* vlb = vl_g + (size_t)di * DPLANE + (size_t)b * (DL * OD) + (size_t)v0 * OD;

    const int wave = tid >> 6;
    const int lane = tid & 63;
    const int l15 = lane & 15;
    const int quad = lane >> 4;

    floatx4 acc[2][2];
#pragma unroll
    for (int i = 0; i < 2; ++i)
#pragma unroll
        for (int j = 0; j < 2; ++j) acc[i][j] = (floatx4)0.f;

    // K = 128 as 4 windows of 32; lane's k-slice = quad*8 within each window.
#pragma unroll
    for (int kw = 0; kw < 4; ++kw) {
        const int ko = kw * 32 + quad * 8;
        short8 qh[2], ql[2], vh[2], vl[2];
#pragma unroll
        for (int i = 0; i < 2; ++i) {
            const int qr = i * 16 + l15;
            const int vr = wave * 32 + i * 16 + l15;
            qh[i] = *reinterpret_cast<const short8*>(qhb + qr * OD + ko);
            ql[i] = *reinterpret_cast<const short8*>(qlb + qr * OD + ko);
            vh[i] = *reinterpret_cast<const short8*>(vhb + (size_t)vr * OD + ko);
            vl[i] = *reinterpret_cast<const short8*>(vlb + (size_t)vr * OD + ko);
        }
#pragma unroll
        for (int i = 0; i < 2; ++i)
#pragma unroll
            for (int j = 0; j < 2; ++j) {
                acc[i][j] = __builtin_amdgcn_mfma_f32_16x16x32_bf16(qh[i], vh[j], acc[i][j], 0, 0, 0);
                acc[i][j] = __builtin_amdgcn_mfma_f32_16x16x32_bf16(qh[i], vl[j], acc[i][j], 0, 0, 0);
                acc[i][j] = __builtin_amdgcn_mfma_f32_16x16x32_bf16(ql[i], vh[j], acc[i][j], 0, 0, 0);
            }
    }

    // ---- S tile to LDS (stride 132 f32), poison v >= vmax with 1e4 ----
    const int vmax = min(128, Vk - v0);
#pragma unroll
    for (int i = 0; i < 2; ++i)
#pragma unroll
        for (int j = 0; j < 2; ++j)
#pragma unroll
            for (int r = 0; r < 4; ++r) {
                int q = i * 16 + quad * 4 + r;
                int v = wave * 32 + j * 16 + l15;
                float val = acc[i][j][r];
                if (v >= vmax) val = 1.0e4f;
                Sm[q * 132 + v] = val;
            }
    __syncthreads();

    // ---- gaussian phase: thread = (q, t), 4 independent accumulators, float4 reads ----
    for (int idx = tid; idx < 32 * KNUM; idx += 256) {
        int q = idx & 31;
        int t = idx >> 5;
        float mu = (t == 0) ? 1.0f : 0.95f - 0.1f * (float)(t - 1);
        float Am = (t == 0) ? -721347.52f : -72.13475204f;   // -log2e/(2 sigma^2)
        const float* srow = &Sm[q * 132];
        float a0 = 0.f, a1 = 0.f, a2 = 0.f, a3 = 0.f;
#pragma unroll 8
        for (int j = 0; j < 32; ++j) {
            float4 s4 = *reinterpret_cast<const float4*>(&srow[4 * j]);
            float d0 = s4.x - mu;
            float d1 = s4.y - mu;
            float d2 = s4.z - mu;
            float d3 = s4.w - mu;
            a0 += __builtin_exp2f(Am * d0 * d0);
            a1 += __builtin_exp2f(Am * d1 * d1);
            a2 += __builtin_exp2f(Am * d2 * d2);
            a3 += __builtin_exp2f(Am * d3 * d3);
        }
        atomicAdd(&accb[((pp * NB + b) * QL + q) * KNUM + t], (a0 + a1) + (a2 + a3));
    }
}

// ---------------- finalize ----------------
__global__ void finalize_kernel(const float* __restrict__ accb,
                                const float* __restrict__ qmask,
                                const float* __restrict__ dw,
                                const float* __restrict__ db,
                                float* __restrict__ out) {
    __shared__ float prod[192];
    int b = blockIdx.x;
    int tid = threadIdx.x;
    if (tid < 189) {
        int pq = tid / 21;
        int t = tid - pq * 21;
        int qi = pq / 3;
        int Qk = 32 - qi;
        const float* ab = accb + ((pq * NB + b) * QL) * KNUM + t;
        float s = 0.f;
        for (int q = 0; q < Qk; ++q)
            s += logf(fmaxf(ab[q * KNUM], 1e-10f)) * qmask[b * QL + q];
        float lg = s * 0.01f;
        out[NB + b * 189 + tid] = lg;
        prod[tid] = lg * dw[tid];
    }
    __syncthreads();
    if (tid == 0) {
        float sc = db[0];
        for (int i = 0; i < 189; ++i) sc += prod[i];
        out[b] = sc;
    }
}

// ---------------- launcher ----------------
extern "C" void kernel_launch(void* const* d_in, const int* in_sizes, int n_in,
                              void* d_out, int out_size, void* d_ws, size_t ws_size,
                              hipStream_t stream) {
    const int* qids = (const int*)d_in[0];
    const float* qmask = (const float*)d_in[1];
    const int* dids = (const int*)d_in[2];
    const float* dmask = (const float*)d_in[3];
    const float* emb = (const float*)d_in[4];
    const float* w1 = (const float*)d_in[5];
    const float* b1 = (const float*)d_in[6];
    const float* w2 = (const float*)d_in[7];
    const float* b2 = (const float*)d_in[8];
    const float* w3 = (const float*)d_in[9];
    const float* b3 = (const float*)d_in[10];
    const float* dw = (const float*)d_in[11];
    const float* db = (const float*)d_in[12];
    float* out = (float*)d_out;
    float* ws = (float*)d_ws;

    ushort* wp  = (ushort*)(ws + WP_OFF);
    ushort* dpk = (ushort*)(ws + DPK_OFF);
    ushort* qpk = (ushort*)(ws + QPK_OFF);
    ushort* qh  = (ushort*)(ws + QH_OFF);
    ushort* qlo = (ushort*)(ws + QLO_OFF);
    ushort* dh  = (ushort*)(ws + DH_OFF);
    ushort* dlo = (ushort*)(ws + DLO_OFF);
    float* accb = ws + ACC_OFF;

    hipMemsetAsync(accb, 0, ACC_SZ * sizeof(float), stream);
    prep_w_kernel<<<960, 256, 0, stream>>>(w1, w2, w3, wp);
    gather_pack<<<((MROWS + 2) * 40 + 255) / 256, 256, 0, stream>>>(emb, dids, qids, dpk, qpk);

    conv_mfma<<<CONV_BLOCKS, 256, 0, stream>>>(dpk, dmask, qmask, wp, b1, b2, b3, dh, dlo, qh, qlo);

    matcher_kernel<<<dim3(8, NB, 9), 256, 0, stream>>>(qh, qlo, dh, dlo, accb);
    finalize_kernel<<<NB, 256, 0, stream>>>(accb, qmask, dw, db, out);
}